// Round 1
// baseline (790.181 us; speedup 1.0000x reference)
//
#include <hip/hip_runtime.h>
#include <hip/hip_bf16.h>
#include <cstdint>
#include <cstddef>

typedef __bf16 bf16;
typedef __bf16 bf16x8 __attribute__((ext_vector_type(8)));
typedef float f32x4 __attribute__((ext_vector_type(4)));

#define N_PTS 131072
#define CDIM  512
#define C3    1536
#define HD    64
#define NH    8
#define KWIN  128

static __device__ __forceinline__ bf16 cvt(float x) { return (bf16)x; }

// ---------------------------------------------------------------------------
// Weight prep: transpose + cast f32 -> bf16.  Wt[col][k] = W[k][col].
// ---------------------------------------------------------------------------
__global__ __launch_bounds__(256) void k_prep(
    const float* __restrict__ Wqkv, const float* __restrict__ Wproj,
    bf16* __restrict__ Wqkv_t, bf16* __restrict__ Wproj_t)
{
    int idx = blockIdx.x * 256 + threadIdx.x;
    if (idx < CDIM * C3) {
        int k = idx / C3, c = idx % C3;
        Wqkv_t[(size_t)c * CDIM + k] = cvt(Wqkv[idx]);
    } else {
        int j = idx - CDIM * C3;
        if (j < CDIM * CDIM) {
            int k = j / CDIM, c = j % CDIM;
            Wproj_t[(size_t)c * CDIM + k] = cvt(Wproj[j]);
        }
    }
}

// ---------------------------------------------------------------------------
// QKV GEMM with fused gather:  qkv_s[i,:] = feat[order[i],:] @ Wqkv + bqkv
// 128x128 tile, BK=32, 4 waves, each wave 64x64 via 4x4 16x16x32 mfma frags.
// ---------------------------------------------------------------------------
__global__ __launch_bounds__(256) void k_qkv(
    const float* __restrict__ feat, const bf16* __restrict__ Wqkv_t,
    const float* __restrict__ bqkv, const int* __restrict__ order,
    bf16* __restrict__ qkv_s)
{
    __shared__ __align__(16) bf16 As[128][40];   // [row][k], pad 40 -> 80B stride
    __shared__ __align__(16) bf16 Bs[128][40];   // [col][k]
    __shared__ int ord_s[128];

    const int t    = threadIdx.x;
    const int lane = t & 63;
    const int wv   = t >> 6;
    const int wr   = wv >> 1, wc = wv & 1;
    const int g    = lane >> 4, r16 = lane & 15;
    const int m0   = blockIdx.y * 128;
    const int n0   = blockIdx.x * 128;

    if (t < 128) ord_s[t] = order[m0 + t];

    f32x4 acc[4][4];
    const f32x4 z = {0.f, 0.f, 0.f, 0.f};
#pragma unroll
    for (int m = 0; m < 4; ++m)
#pragma unroll
        for (int n = 0; n < 4; ++n) acc[m][n] = z;

    __syncthreads();

    for (int k0 = 0; k0 < CDIM; k0 += 32) {
        // stage A: 128 rows x 32 k (f32 gather -> bf16)
#pragma unroll
        for (int it = 0; it < 4; ++it) {
            int s   = it * 256 + t;      // 0..1023
            int row = s >> 3;            // 8 float4-chunks per row
            int c4  = (s & 7) << 2;
            float4 v = *reinterpret_cast<const float4*>(
                feat + (size_t)ord_s[row] * CDIM + k0 + c4);
            union { bf16 e[4]; uint2 u; } pk;
            pk.e[0] = cvt(v.x); pk.e[1] = cvt(v.y);
            pk.e[2] = cvt(v.z); pk.e[3] = cvt(v.w);
            *reinterpret_cast<uint2*>(&As[row][c4]) = pk.u;
        }
        // stage B: 128 cols x 32 k (bf16 copy from pre-transposed weights)
#pragma unroll
        for (int it = 0; it < 2; ++it) {
            int s   = it * 256 + t;      // 0..511
            int col = s >> 2;
            int c8  = (s & 3) << 3;
            *reinterpret_cast<uint4*>(&Bs[col][c8]) =
                *reinterpret_cast<const uint4*>(
                    Wqkv_t + (size_t)(n0 + col) * CDIM + k0 + c8);
        }
        __syncthreads();

        bf16x8 af[4], bf[4];
#pragma unroll
        for (int m = 0; m < 4; ++m)
            af[m] = *reinterpret_cast<const bf16x8*>(&As[wr * 64 + m * 16 + r16][g * 8]);
#pragma unroll
        for (int n = 0; n < 4; ++n)
            bf[n] = *reinterpret_cast<const bf16x8*>(&Bs[wc * 64 + n * 16 + r16][g * 8]);
#pragma unroll
        for (int m = 0; m < 4; ++m)
#pragma unroll
            for (int n = 0; n < 4; ++n)
                acc[m][n] = __builtin_amdgcn_mfma_f32_16x16x32_bf16(
                    af[m], bf[n], acc[m][n], 0, 0, 0);
        __syncthreads();
    }

    // epilogue: D layout col=lane&15, row=(lane>>4)*4+j   [verified layout]
#pragma unroll
    for (int n = 0; n < 4; ++n) {
        int col = n0 + wc * 64 + n * 16 + r16;
        float bias = bqkv[col];
#pragma unroll
        for (int m = 0; m < 4; ++m)
#pragma unroll
            for (int j = 0; j < 4; ++j) {
                int row = m0 + wr * 64 + m * 16 + g * 4 + j;
                qkv_s[(size_t)row * C3 + col] = cvt(acc[m][n][j] + bias);
            }
    }
}

// ---------------------------------------------------------------------------
// Attention: one block per (window, head). 4 waves, each owns 32 query rows.
// LDS: Q[128][72], K[128][72] (unioned with P[128][136]), Vt[64][136].
// ---------------------------------------------------------------------------
__global__ __launch_bounds__(256) void k_attn(
    const bf16* __restrict__ qkv_s, bf16* __restrict__ attn_s)
{
    __shared__ __align__(16) char smem[36864 + 64 * 136 * 2];
    bf16 (*Q)[72]   = reinterpret_cast<bf16 (*)[72]>(smem);
    bf16 (*Kt)[72]  = reinterpret_cast<bf16 (*)[72]>(smem + 128 * 72 * 2);
    bf16 (*P)[136]  = reinterpret_cast<bf16 (*)[136]>(smem);          // overlaps Q,K
    bf16 (*Vt)[136] = reinterpret_cast<bf16 (*)[136]>(smem + 36864);  // V transposed

    const int t    = threadIdx.x;
    const int lane = t & 63;
    const int wv   = t >> 6;
    const int g    = lane >> 4, r16 = lane & 15;
    const int h    = blockIdx.x;
    const int w    = blockIdx.y;

    const bf16* base = qkv_s + (size_t)w * KWIN * C3 + h * HD;

    // stage Q, K (row-major [tok][d]) and V transposed [d][tok]
#pragma unroll
    for (int it = 0; it < 4; ++it) {
        int s   = it * 256 + t;      // 0..1023
        int tok = s >> 3;
        int c8  = (s & 7) << 3;
        size_t roff = (size_t)tok * C3 + c8;
        *reinterpret_cast<uint4*>(&Q[tok][c8])  =
            *reinterpret_cast<const uint4*>(base + roff);
        *reinterpret_cast<uint4*>(&Kt[tok][c8]) =
            *reinterpret_cast<const uint4*>(base + roff + CDIM);
        uint4 vvec = *reinterpret_cast<const uint4*>(base + roff + 2 * CDIM);
        const bf16* ve = reinterpret_cast<const bf16*>(&vvec);
#pragma unroll
        for (int i = 0; i < 8; ++i) Vt[c8 + i][tok] = ve[i];
    }
    __syncthreads();

    // S = Q K^T for rows [wv*32, wv*32+32)
    f32x4 sc[2][8];
    const f32x4 z = {0.f, 0.f, 0.f, 0.f};
#pragma unroll
    for (int m = 0; m < 2; ++m)
#pragma unroll
        for (int n = 0; n < 8; ++n) sc[m][n] = z;

#pragma unroll
    for (int ks = 0; ks < 2; ++ks) {
        bf16x8 aq[2];
#pragma unroll
        for (int m = 0; m < 2; ++m)
            aq[m] = *reinterpret_cast<const bf16x8*>(
                &Q[wv * 32 + m * 16 + r16][ks * 32 + g * 8]);
#pragma unroll
        for (int n = 0; n < 8; ++n) {
            bf16x8 bk = *reinterpret_cast<const bf16x8*>(
                &Kt[n * 16 + r16][ks * 32 + g * 8]);
#pragma unroll
            for (int m = 0; m < 2; ++m)
                sc[m][n] = __builtin_amdgcn_mfma_f32_16x16x32_bf16(
                    aq[m], bk, sc[m][n], 0, 0, 0);
        }
    }

    // softmax (f32). Row r = wv*32 + m*16 + g*4 + j lives in the 16 lanes of
    // group g (r16 = col-within-frag), 8 n-frags each -> 128 cols.
    const float scale = 0.125f;   // hd^-0.5
    float inv_sum[2][4];
#pragma unroll
    for (int m = 0; m < 2; ++m) {
#pragma unroll
        for (int j = 0; j < 4; ++j) {
            float mx = -3.0e38f;
#pragma unroll
            for (int n = 0; n < 8; ++n) mx = fmaxf(mx, sc[m][n][j]);
            mx = fmaxf(mx, __shfl_xor(mx, 1));
            mx = fmaxf(mx, __shfl_xor(mx, 2));
            mx = fmaxf(mx, __shfl_xor(mx, 4));
            mx = fmaxf(mx, __shfl_xor(mx, 8));
            mx *= scale;
            float ssum = 0.f;
#pragma unroll
            for (int n = 0; n < 8; ++n) {
                float p = __expf(sc[m][n][j] * scale - mx);
                sc[m][n][j] = p;
                ssum += p;
            }
            ssum += __shfl_xor(ssum, 1);
            ssum += __shfl_xor(ssum, 2);
            ssum += __shfl_xor(ssum, 4);
            ssum += __shfl_xor(ssum, 8);
            inv_sum[m][j] = 1.f / ssum;
        }
    }

    __syncthreads();   // all waves done reading Q/Kt before P overwrites them

    // write normalized P (bf16) into own 32 rows
#pragma unroll
    for (int m = 0; m < 2; ++m)
#pragma unroll
        for (int n = 0; n < 8; ++n)
#pragma unroll
            for (int j = 0; j < 4; ++j)
                P[wv * 32 + m * 16 + g * 4 + j][n * 16 + r16] =
                    cvt(sc[m][n][j] * inv_sum[m][j]);

    // O = P V   (32x64 per wave)
    f32x4 o[2][4];
#pragma unroll
    for (int m = 0; m < 2; ++m)
#pragma unroll
        for (int n = 0; n < 4; ++n) o[m][n] = z;

#pragma unroll
    for (int kt = 0; kt < 4; ++kt) {
        bf16x8 ap[2];
#pragma unroll
        for (int m = 0; m < 2; ++m)
            ap[m] = *reinterpret_cast<const bf16x8*>(
                &P[wv * 32 + m * 16 + r16][kt * 32 + g * 8]);
#pragma unroll
        for (int n = 0; n < 4; ++n) {
            bf16x8 bv = *reinterpret_cast<const bf16x8*>(
                &Vt[n * 16 + r16][kt * 32 + g * 8]);
#pragma unroll
            for (int m = 0; m < 2; ++m)
                o[m][n] = __builtin_amdgcn_mfma_f32_16x16x32_bf16(
                    ap[m], bv, o[m][n], 0, 0, 0);
        }
    }

    // store attn output, serialized layout [w*128+tok][h*64+d], bf16
#pragma unroll
    for (int m = 0; m < 2; ++m)
#pragma unroll
        for (int n = 0; n < 4; ++n)
#pragma unroll
            for (int j = 0; j < 4; ++j) {
                int tok = wv * 32 + m * 16 + g * 4 + j;
                int d   = n * 16 + r16;
                attn_s[(size_t)(w * KWIN + tok) * CDIM + h * HD + d] =
                    cvt(o[m][n][j]);
            }
}

// ---------------------------------------------------------------------------
// Proj GEMM with fused gather: out[n,:] = attn_s[inverse[n],:] @ Wproj + bproj
// ---------------------------------------------------------------------------
__global__ __launch_bounds__(256) void k_proj(
    const bf16* __restrict__ attn_s, const bf16* __restrict__ Wproj_t,
    const float* __restrict__ bproj, const int* __restrict__ inverse,
    float* __restrict__ out)
{
    __shared__ __align__(16) bf16 As[128][40];
    __shared__ __align__(16) bf16 Bs[128][40];
    __shared__ int inv_s[128];

    const int t    = threadIdx.x;
    const int lane = t & 63;
    const int wv   = t >> 6;
    const int wr   = wv >> 1, wc = wv & 1;
    const int g    = lane >> 4, r16 = lane & 15;
    const int m0   = blockIdx.y * 128;
    const int n0   = blockIdx.x * 128;

    if (t < 128) inv_s[t] = inverse[m0 + t];

    f32x4 acc[4][4];
    const f32x4 z = {0.f, 0.f, 0.f, 0.f};
#pragma unroll
    for (int m = 0; m < 4; ++m)
#pragma unroll
        for (int n = 0; n < 4; ++n) acc[m][n] = z;

    __syncthreads();

    for (int k0 = 0; k0 < CDIM; k0 += 32) {
#pragma unroll
        for (int it = 0; it < 2; ++it) {
            int s   = it * 256 + t;     // 0..511
            int row = s >> 2;
            int c8  = (s & 3) << 3;
            *reinterpret_cast<uint4*>(&As[row][c8]) =
                *reinterpret_cast<const uint4*>(
                    attn_s + (size_t)inv_s[row] * CDIM + k0 + c8);
        }
#pragma unroll
        for (int it = 0; it < 2; ++it) {
            int s   = it * 256 + t;
            int col = s >> 2;
            int c8  = (s & 3) << 3;
            *reinterpret_cast<uint4*>(&Bs[col][c8]) =
                *reinterpret_cast<const uint4*>(
                    Wproj_t + (size_t)(n0 + col) * CDIM + k0 + c8);
        }
        __syncthreads();

        bf16x8 af[4], bf[4];
#pragma unroll
        for (int m = 0; m < 4; ++m)
            af[m] = *reinterpret_cast<const bf16x8*>(&As[wr * 64 + m * 16 + r16][g * 8]);
#pragma unroll
        for (int n = 0; n < 4; ++n)
            bf[n] = *reinterpret_cast<const bf16x8*>(&Bs[wc * 64 + n * 16 + r16][g * 8]);
#pragma unroll
        for (int m = 0; m < 4; ++m)
#pragma unroll
            for (int n = 0; n < 4; ++n)
                acc[m][n] = __builtin_amdgcn_mfma_f32_16x16x32_bf16(
                    af[m], bf[n], acc[m][n], 0, 0, 0);
        __syncthreads();
    }

#pragma unroll
    for (int n = 0; n < 4; ++n) {
        int col = n0 + wc * 64 + n * 16 + r16;
        float bias = bproj[col];
#pragma unroll
        for (int m = 0; m < 4; ++m)
#pragma unroll
            for (int j = 0; j < 4; ++j) {
                int row = m0 + wr * 64 + m * 16 + g * 4 + j;
                out[(size_t)row * CDIM + col] = acc[m][n][j] + bias;
            }
    }
}

// ---------------------------------------------------------------------------
extern "C" void kernel_launch(void* const* d_in, const int* in_sizes, int n_in,
                              void* d_out, int out_size, void* d_ws, size_t ws_size,
                              hipStream_t stream)
{
    const float* feat    = (const float*)d_in[0];
    const float* Wqkv    = (const float*)d_in[1];
    const float* bqkv    = (const float*)d_in[2];
    const float* Wproj   = (const float*)d_in[3];
    const float* bproj   = (const float*)d_in[4];
    const int*   order   = (const int*)d_in[5];
    const int*   inverse = (const int*)d_in[6];
    float* out = (float*)d_out;

    const size_t qkv_bytes  = (size_t)N_PTS * C3 * sizeof(bf16);    // 402.7 MB
    const size_t attn_bytes = (size_t)N_PTS * CDIM * sizeof(bf16);  // 134.2 MB
    const size_t wq_bytes   = (size_t)C3 * CDIM * sizeof(bf16);
    const size_t wp_bytes   = (size_t)CDIM * CDIM * sizeof(bf16);
    if (ws_size < qkv_bytes + attn_bytes + wq_bytes + wp_bytes) return;

    bf16* qkv_s   = (bf16*)d_ws;
    bf16* attn_s  = (bf16*)((char*)d_ws + qkv_bytes);
    bf16* Wqkv_t  = (bf16*)((char*)d_ws + qkv_bytes + attn_bytes);
    bf16* Wproj_t = (bf16*)((char*)d_ws + qkv_bytes + attn_bytes + wq_bytes);

    k_prep<<<dim3((CDIM * C3 + CDIM * CDIM + 255) / 256), 256, 0, stream>>>(
        Wqkv, Wproj, Wqkv_t, Wproj_t);
    k_qkv<<<dim3(C3 / 128, N_PTS / 128), 256, 0, stream>>>(
        feat, Wqkv_t, bqkv, order, qkv_s);
    k_attn<<<dim3(NH, N_PTS / KWIN), 256, 0, stream>>>(qkv_s, attn_s);
    k_proj<<<dim3(CDIM / 128, N_PTS / 128), 256, 0, stream>>>(
        attn_s, Wproj_t, bproj, inverse, out);
}

// Round 2
// 700.806 us; speedup vs baseline: 1.1275x; 1.1275x over previous
//
#include <hip/hip_runtime.h>
#include <hip/hip_bf16.h>
#include <cstdint>
#include <cstddef>

typedef __bf16 bf16;
typedef __bf16 bf16x8 __attribute__((ext_vector_type(8)));
typedef float f32x4 __attribute__((ext_vector_type(4)));

#define N_PTS 131072
#define CDIM  512
#define C3    1536
#define HD    64
#define NH    8
#define KWIN  128

static __device__ __forceinline__ bf16 cvt(float x) { return (bf16)x; }

// async global->LDS, 16B per lane. LDS dest = wave-uniform base + lane*16.
static __device__ __forceinline__ void gld16(const bf16* g, bf16* l) {
    __builtin_amdgcn_global_load_lds(
        (const __attribute__((address_space(1))) void*)g,
        (__attribute__((address_space(3))) void*)l, 16, 0, 0);
}

// ---------------------------------------------------------------------------
// Weight prep: transpose + cast f32 -> bf16.  Wt[col][k] = W[k][col].
// ---------------------------------------------------------------------------
__global__ __launch_bounds__(256) void k_prep(
    const float* __restrict__ Wqkv, const float* __restrict__ Wproj,
    bf16* __restrict__ Wqkv_t, bf16* __restrict__ Wproj_t)
{
    int idx = blockIdx.x * 256 + threadIdx.x;
    if (idx < CDIM * C3) {
        int k = idx / C3, c = idx % C3;
        Wqkv_t[(size_t)c * CDIM + k] = cvt(Wqkv[idx]);
    } else {
        int j = idx - CDIM * C3;
        if (j < CDIM * CDIM) {
            int k = j / CDIM, c = j % CDIM;
            Wproj_t[(size_t)c * CDIM + k] = cvt(Wproj[j]);
        }
    }
}

// ---------------------------------------------------------------------------
// Gather + cast: feat_g[i][:] = bf16(feat[order[i]][:])
// 2 rows per block; 128 threads per row, one float4 each.
// ---------------------------------------------------------------------------
__global__ __launch_bounds__(256) void k_gather(
    const float* __restrict__ feat, const int* __restrict__ order,
    bf16* __restrict__ feat_g)
{
    int row = blockIdx.x * 2 + (threadIdx.x >> 7);
    int c   = (threadIdx.x & 127) << 2;
    int src = order[row];
    float4 v = *reinterpret_cast<const float4*>(feat + (size_t)src * CDIM + c);
    union { bf16 e[4]; uint2 u; } pk;
    pk.e[0] = cvt(v.x); pk.e[1] = cvt(v.y); pk.e[2] = cvt(v.z); pk.e[3] = cvt(v.w);
    *reinterpret_cast<uint2*>(feat_g + (size_t)row * CDIM + c) = pk.u;
}

// ---------------------------------------------------------------------------
// Shared bf16 GEMM template (m97 structure):
//   out[m, n] = A[m, :] @ Bt[n, :]^T + bias[n]
// A sequential bf16 [M][512], Bt pre-transposed bf16 [N][512].
// 128x128 tile, BK=64, 4 waves (2x2), wave = 64x64 via 4x4 16x16x32 frags.
// Staging via global_load_lds(16B) into linear LDS, with pre-swizzled global
// source so that ds_read uses byte ^ ((row&7)<<4)  (bank-conflict-free).
// XCD-chunked block swizzle: consecutive swz ids share the A-panel and the XCD.
// ---------------------------------------------------------------------------
template <bool F32OUT, int NT>
__global__ __launch_bounds__(256) void k_gemm(
    const bf16* __restrict__ Ag, const bf16* __restrict__ Bt,
    const float* __restrict__ bias, void* __restrict__ outp)
{
    __shared__ __align__(16) bf16 As[128 * 64];
    __shared__ __align__(16) bf16 Bs[128 * 64];

    const int t    = threadIdx.x;
    const int lane = t & 63;
    const int wv   = t >> 6;
    const int wr   = wv >> 1, wc = wv & 1;
    const int g    = lane >> 4, r16 = lane & 15;

    const int nwg = gridDim.x;
    const int bid = blockIdx.x;
    const int swz = (bid & 7) * (nwg >> 3) + (bid >> 3);
    const int m0  = (swz / NT) * 128;
    const int n0  = (swz % NT) * 128;

    // per-lane staging source (constant across K-steps except k0):
    // linear chunk c_lin (16B units), source chunk c_src = c_lin ^ ((c_lin>>3)&7)
    int c_lin[4], srow[4], scol[4];
#pragma unroll
    for (int j = 0; j < 4; ++j) {
        c_lin[j] = (wv * 4 + j) * 64 + lane;
        int c_src = c_lin[j] ^ ((c_lin[j] >> 3) & 7);
        srow[j] = c_src >> 3;
        scol[j] = (c_src & 7) << 3;
    }

    f32x4 acc[4][4];
    const f32x4 z = {0.f, 0.f, 0.f, 0.f};
#pragma unroll
    for (int m = 0; m < 4; ++m)
#pragma unroll
        for (int n = 0; n < 4; ++n) acc[m][n] = z;

    for (int k0 = 0; k0 < CDIM; k0 += 64) {
#pragma unroll
        for (int j = 0; j < 4; ++j) {
            gld16(Ag + (size_t)(m0 + srow[j]) * CDIM + k0 + scol[j],
                  &As[(wv * 4 + j) * 512]);
            gld16(Bt + (size_t)(n0 + srow[j]) * CDIM + k0 + scol[j],
                  &Bs[(wv * 4 + j) * 512]);
        }
        __syncthreads();

        bf16x8 af[4][2], bfv[4][2];
#pragma unroll
        for (int m = 0; m < 4; ++m) {
            int row = wr * 64 + m * 16 + r16;
#pragma unroll
            for (int kk = 0; kk < 2; ++kk) {
                int boff = row * 128 + ((kk * 64 + g * 16) ^ ((row & 7) << 4));
                af[m][kk] = *reinterpret_cast<const bf16x8*>(
                    reinterpret_cast<const char*>(As) + boff);
            }
        }
#pragma unroll
        for (int n = 0; n < 4; ++n) {
            int row = wc * 64 + n * 16 + r16;
#pragma unroll
            for (int kk = 0; kk < 2; ++kk) {
                int boff = row * 128 + ((kk * 64 + g * 16) ^ ((row & 7) << 4));
                bfv[n][kk] = *reinterpret_cast<const bf16x8*>(
                    reinterpret_cast<const char*>(Bs) + boff);
            }
        }
#pragma unroll
        for (int kk = 0; kk < 2; ++kk)
#pragma unroll
            for (int m = 0; m < 4; ++m)
#pragma unroll
                for (int n = 0; n < 4; ++n)
                    acc[m][n] = __builtin_amdgcn_mfma_f32_16x16x32_bf16(
                        af[m][kk], bfv[n][kk], acc[m][n], 0, 0, 0);
        __syncthreads();
    }

    // epilogue: D layout col=lane&15, row=(lane>>4)*4+j
    const int ldo = NT * 128;
#pragma unroll
    for (int n = 0; n < 4; ++n) {
        int col = n0 + wc * 64 + n * 16 + r16;
        float b = bias[col];
#pragma unroll
        for (int m = 0; m < 4; ++m)
#pragma unroll
            for (int j = 0; j < 4; ++j) {
                int row = m0 + wr * 64 + m * 16 + g * 4 + j;
                if (F32OUT)
                    reinterpret_cast<float*>(outp)[(size_t)row * ldo + col] =
                        acc[m][n][j] + b;
                else
                    reinterpret_cast<bf16*>(outp)[(size_t)row * ldo + col] =
                        cvt(acc[m][n][j] + b);
            }
    }
}

// ---------------------------------------------------------------------------
// Attention: one block per (window, head). 4 waves, each owns 32 query rows.
// Output rows are SCATTERED to attn_g[order[w*128+tok]] so that k_proj's A
// operand is sequential (order[inverse[n]] == n).
// ---------------------------------------------------------------------------
__global__ __launch_bounds__(256) void k_attn(
    const bf16* __restrict__ qkv_s, const int* __restrict__ order,
    bf16* __restrict__ attn_g)
{
    __shared__ __align__(16) char smem[36864 + 64 * 136 * 2];
    __shared__ int ord_s[KWIN];
    bf16 (*Q)[72]   = reinterpret_cast<bf16 (*)[72]>(smem);
    bf16 (*Kt)[72]  = reinterpret_cast<bf16 (*)[72]>(smem + 128 * 72 * 2);
    bf16 (*P)[136]  = reinterpret_cast<bf16 (*)[136]>(smem);          // overlaps Q,K
    bf16 (*Vt)[136] = reinterpret_cast<bf16 (*)[136]>(smem + 36864);  // V transposed

    const int t    = threadIdx.x;
    const int lane = t & 63;
    const int wv   = t >> 6;
    const int g    = lane >> 4, r16 = lane & 15;
    const int h    = blockIdx.x;
    const int w    = blockIdx.y;

    const bf16* base = qkv_s + (size_t)w * KWIN * C3 + h * HD;

    if (t < KWIN) ord_s[t] = order[w * KWIN + t];

    // stage Q, K (row-major [tok][d]) and V transposed [d][tok]
#pragma unroll
    for (int it = 0; it < 4; ++it) {
        int s   = it * 256 + t;      // 0..1023
        int tok = s >> 3;
        int c8  = (s & 7) << 3;
        size_t roff = (size_t)tok * C3 + c8;
        *reinterpret_cast<uint4*>(&Q[tok][c8])  =
            *reinterpret_cast<const uint4*>(base + roff);
        *reinterpret_cast<uint4*>(&Kt[tok][c8]) =
            *reinterpret_cast<const uint4*>(base + roff + CDIM);
        uint4 vvec = *reinterpret_cast<const uint4*>(base + roff + 2 * CDIM);
        const bf16* ve = reinterpret_cast<const bf16*>(&vvec);
#pragma unroll
        for (int i = 0; i < 8; ++i) Vt[c8 + i][tok] = ve[i];
    }
    __syncthreads();

    // S = Q K^T for rows [wv*32, wv*32+32)
    f32x4 sc[2][8];
    const f32x4 z = {0.f, 0.f, 0.f, 0.f};
#pragma unroll
    for (int m = 0; m < 2; ++m)
#pragma unroll
        for (int n = 0; n < 8; ++n) sc[m][n] = z;

#pragma unroll
    for (int ks = 0; ks < 2; ++ks) {
        bf16x8 aq[2];
#pragma unroll
        for (int m = 0; m < 2; ++m)
            aq[m] = *reinterpret_cast<const bf16x8*>(
                &Q[wv * 32 + m * 16 + r16][ks * 32 + g * 8]);
#pragma unroll
        for (int n = 0; n < 8; ++n) {
            bf16x8 bk = *reinterpret_cast<const bf16x8*>(
                &Kt[n * 16 + r16][ks * 32 + g * 8]);
#pragma unroll
            for (int m = 0; m < 2; ++m)
                sc[m][n] = __builtin_amdgcn_mfma_f32_16x16x32_bf16(
                    aq[m], bk, sc[m][n], 0, 0, 0);
        }
    }

    // softmax (f32), row-parallel over 16-lane groups
    const float scale = 0.125f;   // hd^-0.5
    float inv_sum[2][4];
#pragma unroll
    for (int m = 0; m < 2; ++m) {
#pragma unroll
        for (int j = 0; j < 4; ++j) {
            float mx = -3.0e38f;
#pragma unroll
            for (int n = 0; n < 8; ++n) mx = fmaxf(mx, sc[m][n][j]);
            mx = fmaxf(mx, __shfl_xor(mx, 1));
            mx = fmaxf(mx, __shfl_xor(mx, 2));
            mx = fmaxf(mx, __shfl_xor(mx, 4));
            mx = fmaxf(mx, __shfl_xor(mx, 8));
            mx *= scale;
            float ssum = 0.f;
#pragma unroll
            for (int n = 0; n < 8; ++n) {
                float p = __expf(sc[m][n][j] * scale - mx);
                sc[m][n][j] = p;
                ssum += p;
            }
            ssum += __shfl_xor(ssum, 1);
            ssum += __shfl_xor(ssum, 2);
            ssum += __shfl_xor(ssum, 4);
            ssum += __shfl_xor(ssum, 8);
            inv_sum[m][j] = 1.f / ssum;
        }
    }

    __syncthreads();   // all waves done reading Q/Kt before P overwrites them

    // write normalized P (bf16)
#pragma unroll
    for (int m = 0; m < 2; ++m)
#pragma unroll
        for (int n = 0; n < 8; ++n)
#pragma unroll
            for (int j = 0; j < 4; ++j)
                P[wv * 32 + m * 16 + g * 4 + j][n * 16 + r16] =
                    cvt(sc[m][n][j] * inv_sum[m][j]);

    // O = P V   (32x64 per wave)
    f32x4 o[2][4];
#pragma unroll
    for (int m = 0; m < 2; ++m)
#pragma unroll
        for (int n = 0; n < 4; ++n) o[m][n] = z;

#pragma unroll
    for (int kt = 0; kt < 4; ++kt) {
        bf16x8 ap[2];
#pragma unroll
        for (int m = 0; m < 2; ++m)
            ap[m] = *reinterpret_cast<const bf16x8*>(
                &P[wv * 32 + m * 16 + r16][kt * 32 + g * 8]);
#pragma unroll
        for (int n = 0; n < 4; ++n) {
            bf16x8 bv = *reinterpret_cast<const bf16x8*>(
                &Vt[n * 16 + r16][kt * 32 + g * 8]);
#pragma unroll
            for (int m = 0; m < 2; ++m)
                o[m][n] = __builtin_amdgcn_mfma_f32_16x16x32_bf16(
                    ap[m], bv, o[m][n], 0, 0, 0);
        }
    }

    // scatter rows to unserialized position: attn_g[order[i]] = ser[i]
#pragma unroll
    for (int m = 0; m < 2; ++m)
#pragma unroll
        for (int n = 0; n < 4; ++n)
#pragma unroll
            for (int j = 0; j < 4; ++j) {
                int tok  = wv * 32 + m * 16 + g * 4 + j;
                int d    = n * 16 + r16;
                int drow = ord_s[tok];
                attn_g[(size_t)drow * CDIM + h * HD + d] = cvt(o[m][n][j]);
            }
}

// ---------------------------------------------------------------------------
extern "C" void kernel_launch(void* const* d_in, const int* in_sizes, int n_in,
                              void* d_out, int out_size, void* d_ws, size_t ws_size,
                              hipStream_t stream)
{
    const float* feat    = (const float*)d_in[0];
    const float* Wqkv    = (const float*)d_in[1];
    const float* bqkv    = (const float*)d_in[2];
    const float* Wproj   = (const float*)d_in[3];
    const float* bproj   = (const float*)d_in[4];
    const int*   order   = (const int*)d_in[5];
    float* out = (float*)d_out;

    const size_t qkv_bytes  = (size_t)N_PTS * C3 * sizeof(bf16);    // 402.7 MB
    const size_t gat_bytes  = (size_t)N_PTS * CDIM * sizeof(bf16);  // 134.2 MB (feat_g / attn_g)
    const size_t wq_bytes   = (size_t)C3 * CDIM * sizeof(bf16);
    const size_t wp_bytes   = (size_t)CDIM * CDIM * sizeof(bf16);
    if (ws_size < qkv_bytes + gat_bytes + wq_bytes + wp_bytes) return;

    bf16* qkv_s   = (bf16*)d_ws;
    bf16* shared134 = (bf16*)((char*)d_ws + qkv_bytes);   // feat_g, later attn_g
    bf16* Wqkv_t  = (bf16*)((char*)d_ws + qkv_bytes + gat_bytes);
    bf16* Wproj_t = (bf16*)((char*)d_ws + qkv_bytes + gat_bytes + wq_bytes);

    k_prep<<<dim3((CDIM * C3 + CDIM * CDIM + 255) / 256), 256, 0, stream>>>(
        Wqkv, Wproj, Wqkv_t, Wproj_t);
    k_gather<<<dim3(N_PTS / 2), 256, 0, stream>>>(feat, order, shared134);
    // qkv GEMM: [131072 x 1536] = feat_g @ Wqkv_t^T
    k_gemm<false, C3 / 128><<<dim3((N_PTS / 128) * (C3 / 128)), 256, 0, stream>>>(
        shared134, Wqkv_t, bqkv, qkv_s);
    // attention (reads qkv_s, scatters into shared134 = attn_g)
    k_attn<<<dim3(NH, N_PTS / KWIN), 256, 0, stream>>>(qkv_s, order, shared134);
    // proj GEMM: [131072 x 512] = attn_g @ Wproj_t^T  (f32 out)
    k_gemm<true, CDIM / 128><<<dim3((N_PTS / 128) * (CDIM / 128)), 256, 0, stream>>>(
        shared134, Wproj_t, bproj, out);
}

// Round 3
// 664.835 us; speedup vs baseline: 1.1885x; 1.0541x over previous
//
#include <hip/hip_runtime.h>
#include <hip/hip_bf16.h>
#include <cstdint>
#include <cstddef>

typedef __bf16 bf16;
typedef __bf16 bf16x8 __attribute__((ext_vector_type(8)));
typedef float f32x4 __attribute__((ext_vector_type(4)));

#define N_PTS 131072
#define CDIM  512
#define C3    1536
#define HD    64
#define NH    8
#define KWIN  128

static __device__ __forceinline__ bf16 cvt(float x) { return (bf16)x; }

// async global->LDS, 16B per lane. LDS dest = wave-uniform base + lane*16.
static __device__ __forceinline__ void gld16(const bf16* g, bf16* l) {
    __builtin_amdgcn_global_load_lds(
        (const __attribute__((address_space(1))) void*)g,
        (__attribute__((address_space(3))) void*)l, 16, 0, 0);
}

// ---------------------------------------------------------------------------
// Weight prep: transpose + cast f32 -> bf16.  Wt[col][k] = W[k][col].
// ---------------------------------------------------------------------------
__global__ __launch_bounds__(256) void k_prep(
    const float* __restrict__ Wqkv, const float* __restrict__ Wproj,
    bf16* __restrict__ Wqkv_t, bf16* __restrict__ Wproj_t)
{
    int idx = blockIdx.x * 256 + threadIdx.x;
    if (idx < CDIM * C3) {
        int k = idx / C3, c = idx % C3;
        Wqkv_t[(size_t)c * CDIM + k] = cvt(Wqkv[idx]);
    } else {
        int j = idx - CDIM * C3;
        if (j < CDIM * CDIM) {
            int k = j / CDIM, c = j % CDIM;
            Wproj_t[(size_t)c * CDIM + k] = cvt(Wproj[j]);
        }
    }
}

// ---------------------------------------------------------------------------
// Gather + cast: feat_g[i][:] = bf16(feat[order[i]][:])
// ---------------------------------------------------------------------------
__global__ __launch_bounds__(256) void k_gather(
    const float* __restrict__ feat, const int* __restrict__ order,
    bf16* __restrict__ feat_g)
{
    int row = blockIdx.x * 2 + (threadIdx.x >> 7);
    int c   = (threadIdx.x & 127) << 2;
    int src = order[row];
    float4 v = *reinterpret_cast<const float4*>(feat + (size_t)src * CDIM + c);
    union { bf16 e[4]; uint2 u; } pk;
    pk.e[0] = cvt(v.x); pk.e[1] = cvt(v.y); pk.e[2] = cvt(v.z); pk.e[3] = cvt(v.w);
    *reinterpret_cast<uint2*>(feat_g + (size_t)row * CDIM + c) = pk.u;
}

// ---------------------------------------------------------------------------
// Deep-pipelined bf16 GEMM (T3+T4 counted-vmcnt schedule):
//   out[m, n] = A[m, :] @ Bt[n, :]^T + bias[n]
// 256x256 tile, BK=32, 8 waves (2M x 4N), wave owns 128x64 C (8x4 frags).
// 4-deep LDS ring (4 x (A 16KB + B 16KB) = 128KB), stage lead = 3 K-tiles.
// Per wave per tile: 4 gld16 staged, 12 ds_read_b128, 32 MFMA.
// vmcnt(8) per tile confirms tile kt+1 while kt+2/kt+3 stay in flight.
// BK=32 => 64B LDS row stride => frag reads already uniform across bank
// quads (8 lanes/quad = b128 floor) — no swizzle needed, staging stays linear.
// ---------------------------------------------------------------------------
template <bool F32OUT, int NT>
__global__ __launch_bounds__(512) void k_gemm(
    const bf16* __restrict__ Ag, const bf16* __restrict__ Bt,
    const float* __restrict__ bias, void* __restrict__ outp)
{
    __shared__ __align__(16) bf16 As[4][256 * 32];
    __shared__ __align__(16) bf16 Bs[4][256 * 32];

    const int t    = threadIdx.x;
    const int lane = t & 63;
    const int wv   = t >> 6;          // 0..7
    const int wr   = wv >> 2;         // 0..1  (M half)
    const int wc   = wv & 3;          // 0..3  (N quarter)
    const int g    = lane >> 4, r16 = lane & 15;

    const int nwg = gridDim.x;
    const int bid = blockIdx.x;
    const int swz = (bid & 7) * (nwg >> 3) + (bid >> 3);  // grids are %8==0
    const int m0  = (swz / NT) * 256;
    const int n0  = (swz % NT) * 256;

    // staging: thread owns 16B chunks L0 and L1 of each operand tile.
    // chunk L -> row = L>>2, 16B-slot s = L&3 (linear, no swizzle).
    const int L0 = wv * 64 + lane;        // 0..511   (rows 0..127)
    const int L1 = L0 + 512;              // 512..1023 (rows 128..255)
    const bf16* sA0 = Ag + (size_t)(m0 + (L0 >> 2)) * CDIM + (L0 & 3) * 8;
    const bf16* sA1 = Ag + (size_t)(m0 + (L1 >> 2)) * CDIM + (L1 & 3) * 8;
    const bf16* sB0 = Bt + (size_t)(n0 + (L0 >> 2)) * CDIM + (L0 & 3) * 8;
    const bf16* sB1 = Bt + (size_t)(n0 + (L1 >> 2)) * CDIM + (L1 & 3) * 8;

    // fragment read byte-offsets within a buffer (row*64 + g*16)
    int aoff[8], boff[4];
#pragma unroll
    for (int i = 0; i < 8; ++i) {
        int row = wr * 128 + i * 16 + r16;
        aoff[i] = row * 64 + g * 16;
    }
#pragma unroll
    for (int n = 0; n < 4; ++n) {
        int row = wc * 64 + n * 16 + r16;
        boff[n] = row * 64 + g * 16;
    }

    f32x4 acc[8][4];
    const f32x4 z = {0.f, 0.f, 0.f, 0.f};
#pragma unroll
    for (int i = 0; i < 8; ++i)
#pragma unroll
        for (int n = 0; n < 4; ++n) acc[i][n] = z;

    auto stage = [&](int kt) {
        const int b  = kt & 3;
        const int ko = kt * 32;
        gld16(sA0 + ko, &As[b][(size_t)wv * 64 * 8]);
        gld16(sA1 + ko, &As[b][(size_t)(512 + wv * 64) * 8]);
        gld16(sB0 + ko, &Bs[b][(size_t)wv * 64 * 8]);
        gld16(sB1 + ko, &Bs[b][(size_t)(512 + wv * 64) * 8]);
    };

    auto compute = [&](int kt) {
        const int b = kt & 3;
        bf16x8 af[8], bv[4];
#pragma unroll
        for (int i = 0; i < 8; ++i)
            af[i] = *reinterpret_cast<const bf16x8*>(
                reinterpret_cast<const char*>(&As[b][0]) + aoff[i]);
#pragma unroll
        for (int n = 0; n < 4; ++n)
            bv[n] = *reinterpret_cast<const bf16x8*>(
                reinterpret_cast<const char*>(&Bs[b][0]) + boff[n]);
        asm volatile("s_waitcnt lgkmcnt(0)" ::: "memory");
        __builtin_amdgcn_sched_barrier(0);   // rule #18: pin MFMA below the wait
        __builtin_amdgcn_s_setprio(1);
#pragma unroll
        for (int i = 0; i < 8; ++i)
#pragma unroll
            for (int n = 0; n < 4; ++n)
                acc[i][n] = __builtin_amdgcn_mfma_f32_16x16x32_bf16(
                    af[i], bv[n], acc[i][n], 0, 0, 0);
        __builtin_amdgcn_s_setprio(0);
    };

    // prologue: stage tiles 0..2, confirm tile 0 (12 issued, wait to 8)
    stage(0); stage(1); stage(2);
    asm volatile("s_waitcnt vmcnt(8)" ::: "memory");
    __builtin_amdgcn_s_barrier();
    __builtin_amdgcn_sched_barrier(0);

    // main loop: tiles 0..12 with full 3-tile lead.
    // at end of tile kt: outstanding = {kt+1, kt+2, kt+3} = 12 loads;
    // vmcnt(8) retires the oldest 4 = tile kt+1. Never drains to 0.
#pragma unroll
    for (int kt = 0; kt < 13; ++kt) {
        stage(kt + 3);
        compute(kt);
        asm volatile("s_waitcnt vmcnt(8)" ::: "memory");
        __builtin_amdgcn_s_barrier();
        __builtin_amdgcn_sched_barrier(0);
    }
    // tail: no more stages; drain 8 -> 4 -> 0
    compute(13);
    asm volatile("s_waitcnt vmcnt(4)" ::: "memory");
    __builtin_amdgcn_s_barrier();
    __builtin_amdgcn_sched_barrier(0);
    compute(14);
    asm volatile("s_waitcnt vmcnt(0)" ::: "memory");
    __builtin_amdgcn_s_barrier();
    __builtin_amdgcn_sched_barrier(0);
    compute(15);

    // epilogue: D layout col=lane&15, row=(lane>>4)*4+j
    const int ldo = NT * 256;
#pragma unroll
    for (int n = 0; n < 4; ++n) {
        int col = n0 + wc * 64 + n * 16 + r16;
        float b = bias[col];
#pragma unroll
        for (int i = 0; i < 8; ++i)
#pragma unroll
            for (int j = 0; j < 4; ++j) {
                int row = m0 + wr * 128 + i * 16 + g * 4 + j;
                if (F32OUT)
                    reinterpret_cast<float*>(outp)[(size_t)row * ldo + col] =
                        acc[i][n][j] + b;
                else
                    reinterpret_cast<bf16*>(outp)[(size_t)row * ldo + col] =
                        cvt(acc[i][n][j] + b);
            }
    }
}

// ---------------------------------------------------------------------------
// Attention: one block per (window, head). 4 waves, each owns 32 query rows.
// Output rows are SCATTERED to attn_g[order[w*128+tok]] so that k_proj's A
// operand is sequential (order[inverse[n]] == n).
// ---------------------------------------------------------------------------
__global__ __launch_bounds__(256) void k_attn(
    const bf16* __restrict__ qkv_s, const int* __restrict__ order,
    bf16* __restrict__ attn_g)
{
    __shared__ __align__(16) char smem[36864 + 64 * 136 * 2];
    __shared__ int ord_s[KWIN];
    bf16 (*Q)[72]   = reinterpret_cast<bf16 (*)[72]>(smem);
    bf16 (*Kt)[72]  = reinterpret_cast<bf16 (*)[72]>(smem + 128 * 72 * 2);
    bf16 (*P)[136]  = reinterpret_cast<bf16 (*)[136]>(smem);          // overlaps Q,K
    bf16 (*Vt)[136] = reinterpret_cast<bf16 (*)[136]>(smem + 36864);  // V transposed

    const int t    = threadIdx.x;
    const int lane = t & 63;
    const int wv   = t >> 6;
    const int g    = lane >> 4, r16 = lane & 15;
    const int h    = blockIdx.x;
    const int w    = blockIdx.y;

    const bf16* base = qkv_s + (size_t)w * KWIN * C3 + h * HD;

    if (t < KWIN) ord_s[t] = order[w * KWIN + t];

    // stage Q, K (row-major [tok][d]) and V transposed [d][tok]
#pragma unroll
    for (int it = 0; it < 4; ++it) {
        int s   = it * 256 + t;      // 0..1023
        int tok = s >> 3;
        int c8  = (s & 7) << 3;
        size_t roff = (size_t)tok * C3 + c8;
        *reinterpret_cast<uint4*>(&Q[tok][c8])  =
            *reinterpret_cast<const uint4*>(base + roff);
        *reinterpret_cast<uint4*>(&Kt[tok][c8]) =
            *reinterpret_cast<const uint4*>(base + roff + CDIM);
        uint4 vvec = *reinterpret_cast<const uint4*>(base + roff + 2 * CDIM);
        const bf16* ve = reinterpret_cast<const bf16*>(&vvec);
#pragma unroll
        for (int i = 0; i < 8; ++i) Vt[c8 + i][tok] = ve[i];
    }
    __syncthreads();

    // S = Q K^T for rows [wv*32, wv*32+32)
    f32x4 sc[2][8];
    const f32x4 z = {0.f, 0.f, 0.f, 0.f};
#pragma unroll
    for (int m = 0; m < 2; ++m)
#pragma unroll
        for (int n = 0; n < 8; ++n) sc[m][n] = z;

#pragma unroll
    for (int ks = 0; ks < 2; ++ks) {
        bf16x8 aq[2];
#pragma unroll
        for (int m = 0; m < 2; ++m)
            aq[m] = *reinterpret_cast<const bf16x8*>(
                &Q[wv * 32 + m * 16 + r16][ks * 32 + g * 8]);
#pragma unroll
        for (int n = 0; n < 8; ++n) {
            bf16x8 bk = *reinterpret_cast<const bf16x8*>(
                &Kt[n * 16 + r16][ks * 32 + g * 8]);
#pragma unroll
            for (int m = 0; m < 2; ++m)
                sc[m][n] = __builtin_amdgcn_mfma_f32_16x16x32_bf16(
                    aq[m], bk, sc[m][n], 0, 0, 0);
        }
    }

    // softmax (f32), row-parallel over 16-lane groups
    const float scale = 0.125f;   // hd^-0.5
    float inv_sum[2][4];
#pragma unroll
    for (int m = 0; m < 2; ++m) {
#pragma unroll
        for (int j = 0; j < 4; ++j) {
            float mx = -3.0e38f;
#pragma unroll
            for (int n = 0; n < 8; ++n) mx = fmaxf(mx, sc[m][n][j]);
            mx = fmaxf(mx, __shfl_xor(mx, 1));
            mx = fmaxf(mx, __shfl_xor(mx, 2));
            mx = fmaxf(mx, __shfl_xor(mx, 4));
            mx = fmaxf(mx, __shfl_xor(mx, 8));
            mx *= scale;
            float ssum = 0.f;
#pragma unroll
            for (int n = 0; n < 8; ++n) {
                float p = __expf(sc[m][n][j] * scale - mx);
                sc[m][n][j] = p;
                ssum += p;
            }
            ssum += __shfl_xor(ssum, 1);
            ssum += __shfl_xor(ssum, 2);
            ssum += __shfl_xor(ssum, 4);
            ssum += __shfl_xor(ssum, 8);
            inv_sum[m][j] = 1.f / ssum;
        }
    }

    __syncthreads();   // all waves done reading Q/Kt before P overwrites them

    // write normalized P (bf16)
#pragma unroll
    for (int m = 0; m < 2; ++m)
#pragma unroll
        for (int n = 0; n < 8; ++n)
#pragma unroll
            for (int j = 0; j < 4; ++j)
                P[wv * 32 + m * 16 + g * 4 + j][n * 16 + r16] =
                    cvt(sc[m][n][j] * inv_sum[m][j]);

    // O = P V   (32x64 per wave)
    f32x4 o[2][4];
#pragma unroll
    for (int m = 0; m < 2; ++m)
#pragma unroll
        for (int n = 0; n < 4; ++n) o[m][n] = z;

#pragma unroll
    for (int kt = 0; kt < 4; ++kt) {
        bf16x8 ap[2];
#pragma unroll
        for (int m = 0; m < 2; ++m)
            ap[m] = *reinterpret_cast<const bf16x8*>(
                &P[wv * 32 + m * 16 + r16][kt * 32 + g * 8]);
#pragma unroll
        for (int n = 0; n < 4; ++n) {
            bf16x8 bv = *reinterpret_cast<const bf16x8*>(
                &Vt[n * 16 + r16][kt * 32 + g * 8]);
#pragma unroll
            for (int m = 0; m < 2; ++m)
                o[m][n] = __builtin_amdgcn_mfma_f32_16x16x32_bf16(
                    ap[m], bv, o[m][n], 0, 0, 0);
        }
    }

    // scatter rows to unserialized position: attn_g[order[i]] = ser[i]
#pragma unroll
    for (int m = 0; m < 2; ++m)
#pragma unroll
        for (int n = 0; n < 4; ++n)
#pragma unroll
            for (int j = 0; j < 4; ++j) {
                int tok  = wv * 32 + m * 16 + g * 4 + j;
                int d    = n * 16 + r16;
                int drow = ord_s[tok];
                attn_g[(size_t)drow * CDIM + h * HD + d] = cvt(o[m][n][j]);
            }
}

// ---------------------------------------------------------------------------
extern "C" void kernel_launch(void* const* d_in, const int* in_sizes, int n_in,
                              void* d_out, int out_size, void* d_ws, size_t ws_size,
                              hipStream_t stream)
{
    const float* feat    = (const float*)d_in[0];
    const float* Wqkv    = (const float*)d_in[1];
    const float* bqkv    = (const float*)d_in[2];
    const float* Wproj   = (const float*)d_in[3];
    const float* bproj   = (const float*)d_in[4];
    const int*   order   = (const int*)d_in[5];
    float* out = (float*)d_out;

    const size_t qkv_bytes  = (size_t)N_PTS * C3 * sizeof(bf16);    // 402.7 MB
    const size_t gat_bytes  = (size_t)N_PTS * CDIM * sizeof(bf16);  // 134.2 MB (feat_g / attn_g)
    const size_t wq_bytes   = (size_t)C3 * CDIM * sizeof(bf16);
    const size_t wp_bytes   = (size_t)CDIM * CDIM * sizeof(bf16);
    if (ws_size < qkv_bytes + gat_bytes + wq_bytes + wp_bytes) return;

    bf16* qkv_s     = (bf16*)d_ws;
    bf16* shared134 = (bf16*)((char*)d_ws + qkv_bytes);   // feat_g, later attn_g
    bf16* Wqkv_t    = (bf16*)((char*)d_ws + qkv_bytes + gat_bytes);
    bf16* Wproj_t   = (bf16*)((char*)d_ws + qkv_bytes + gat_bytes + wq_bytes);

    k_prep<<<dim3((CDIM * C3 + CDIM * CDIM + 255) / 256), 256, 0, stream>>>(
        Wqkv, Wproj, Wqkv_t, Wproj_t);
    k_gather<<<dim3(N_PTS / 2), 256, 0, stream>>>(feat, order, shared134);
    // qkv GEMM: [131072 x 1536] = feat_g @ Wqkv_t^T   (3072 blocks, %8==0)
    k_gemm<false, C3 / 256><<<dim3((N_PTS / 256) * (C3 / 256)), 512, 0, stream>>>(
        shared134, Wqkv_t, bqkv, qkv_s);
    // attention (reads qkv_s, scatters into shared134 = attn_g)
    k_attn<<<dim3(NH, N_PTS / KWIN), 256, 0, stream>>>(qkv_s, order, shared134);
    // proj GEMM: [131072 x 512] = attn_g @ Wproj_t^T  (1024 blocks, f32 out)
    k_gemm<true, CDIM / 256><<<dim3((N_PTS / 256) * (CDIM / 256)), 512, 0, stream>>>(
        shared134, Wproj_t, bproj, out);
}

// Round 4
// 656.461 us; speedup vs baseline: 1.2037x; 1.0128x over previous
//
#include <hip/hip_runtime.h>
#include <hip/hip_bf16.h>
#include <cstdint>
#include <cstddef>

typedef __bf16 bf16;
typedef __bf16 bf16x8 __attribute__((ext_vector_type(8)));
typedef float f32x4 __attribute__((ext_vector_type(4)));

#define N_PTS 131072
#define CDIM  512
#define C3    1536
#define HD    64
#define NH    8
#define KWIN  128

static __device__ __forceinline__ bf16 cvt(float x) { return (bf16)x; }

// async global->LDS, 16B per lane. LDS dest = wave-uniform base + lane*16.
static __device__ __forceinline__ void gld16(const bf16* g, bf16* l) {
    __builtin_amdgcn_global_load_lds(
        (const __attribute__((address_space(1))) void*)g,
        (__attribute__((address_space(3))) void*)l, 16, 0, 0);
}

// ---------------------------------------------------------------------------
// Weight prep: transpose + cast f32 -> bf16.  Wt[col][k] = W[k][col].
// ---------------------------------------------------------------------------
__global__ __launch_bounds__(256) void k_prep(
    const float* __restrict__ Wqkv, const float* __restrict__ Wproj,
    bf16* __restrict__ Wqkv_t, bf16* __restrict__ Wproj_t)
{
    int idx = blockIdx.x * 256 + threadIdx.x;
    if (idx < CDIM * C3) {
        int k = idx / C3, c = idx % C3;
        Wqkv_t[(size_t)c * CDIM + k] = cvt(Wqkv[idx]);
    } else {
        int j = idx - CDIM * C3;
        if (j < CDIM * CDIM) {
            int k = j / CDIM, c = j % CDIM;
            Wproj_t[(size_t)c * CDIM + k] = cvt(Wproj[j]);
        }
    }
}

// ---------------------------------------------------------------------------
// Gather + cast: feat_g[i][:] = bf16(feat[order[i]][:])
// ---------------------------------------------------------------------------
__global__ __launch_bounds__(256) void k_gather(
    const float* __restrict__ feat, const int* __restrict__ order,
    bf16* __restrict__ feat_g)
{
    int row = blockIdx.x * 2 + (threadIdx.x >> 7);
    int c   = (threadIdx.x & 127) << 2;
    int src = order[row];
    float4 v = *reinterpret_cast<const float4*>(feat + (size_t)src * CDIM + c);
    union { bf16 e[4]; uint2 u; } pk;
    pk.e[0] = cvt(v.x); pk.e[1] = cvt(v.y); pk.e[2] = cvt(v.z); pk.e[3] = cvt(v.w);
    *reinterpret_cast<uint2*>(feat_g + (size_t)row * CDIM + c) = pk.u;
}

// ---------------------------------------------------------------------------
// Deep-pipelined bf16 GEMM (T3+T4 counted-vmcnt schedule):
//   out[m, n] = A[m, :] @ Bt[n, :]^T + bias[n]
// 256x256 tile, BK=32, 8 waves (2M x 4N), wave owns 128x64 C (8x4 frags).
// 4-deep LDS ring (128KB), stage lead = 3 K-tiles, vmcnt(8) per tile.
//
// LDS layout (rotate-permute, conflict-free): each 256x32 tile buffer is
// 1024 chunks of 16B; chunk (row*4 + p) holds k-slot (p - (row>>1))&3 of row.
// Reader for k-group g uses byte = row*64 + (((g + (row>>1))&3)<<4): the 16
// rows of a frag read spread over all 8 bank-quads (2-way = free).
// Staging applies the inverse permutation to the per-lane GLOBAL source
// (both-sides-or-neither); LDS dest stays linear for global_load_lds.
//
// compute() has NO internal fences: ds_reads are IR loads, the compiler
// interleaves them under the MFMAs with counted lgkmcnt. Buffer-WAR safety
// comes from the combined `s_waitcnt vmcnt(8) lgkmcnt(0)` (memory clobber)
// before each s_barrier — loads cannot hoist across it.
// ---------------------------------------------------------------------------
template <bool F32OUT, int NT>
__global__ __launch_bounds__(512) void k_gemm(
    const bf16* __restrict__ Ag, const bf16* __restrict__ Bt,
    const float* __restrict__ bias, void* __restrict__ outp)
{
    __shared__ __align__(16) bf16 As[4][256 * 32];
    __shared__ __align__(16) bf16 Bs[4][256 * 32];

    const int t    = threadIdx.x;
    const int lane = t & 63;
    const int wv   = t >> 6;          // 0..7
    const int wr   = wv >> 2;         // 0..1  (M half)
    const int wc   = wv & 3;          // 0..3  (N quarter)
    const int g    = lane >> 4, r16 = lane & 15;

    const int nwg = gridDim.x;
    const int bid = blockIdx.x;
    const int swz = (bid & 7) * (nwg >> 3) + (bid >> 3);  // grids are %8==0
    const int m0  = (swz / NT) * 256;
    const int n0  = (swz % NT) * 256;

    // staging: thread owns linear 16B chunks L0, L1 of each operand tile.
    // chunk L: row = L>>2, physical slot p = L&3, source k-slot = (p-(row>>1))&3.
    const int L0 = wv * 64 + lane;        // 0..511   (rows 0..127)
    const int L1 = L0 + 512;              // 512..1023 (rows 128..255)
    const int r0 = L0 >> 2, s0 = ((L0 & 3) - (r0 >> 1)) & 3;
    const int r1 = L1 >> 2, s1 = ((L1 & 3) - (r1 >> 1)) & 3;
    const bf16* sA0 = Ag + (size_t)(m0 + r0) * CDIM + s0 * 8;
    const bf16* sA1 = Ag + (size_t)(m0 + r1) * CDIM + s1 * 8;
    const bf16* sB0 = Bt + (size_t)(n0 + r0) * CDIM + s0 * 8;
    const bf16* sB1 = Bt + (size_t)(n0 + r1) * CDIM + s1 * 8;

    // fragment read byte-offsets (rotate-permuted slots)
    int aoff[8], boff[4];
#pragma unroll
    for (int i = 0; i < 8; ++i) {
        int row = wr * 128 + i * 16 + r16;
        aoff[i] = row * 64 + (((g + (row >> 1)) & 3) << 4);
    }
#pragma unroll
    for (int n = 0; n < 4; ++n) {
        int row = wc * 64 + n * 16 + r16;
        boff[n] = row * 64 + (((g + (row >> 1)) & 3) << 4);
    }

    f32x4 acc[8][4];
    const f32x4 z = {0.f, 0.f, 0.f, 0.f};
#pragma unroll
    for (int i = 0; i < 8; ++i)
#pragma unroll
        for (int n = 0; n < 4; ++n) acc[i][n] = z;

    auto stage = [&](int kt) {
        const int b  = kt & 3;
        const int ko = kt * 32;
        gld16(sA0 + ko, &As[b][(size_t)wv * 64 * 8]);
        gld16(sA1 + ko, &As[b][(size_t)(512 + wv * 64) * 8]);
        gld16(sB0 + ko, &Bs[b][(size_t)wv * 64 * 8]);
        gld16(sB1 + ko, &Bs[b][(size_t)(512 + wv * 64) * 8]);
    };

    auto compute = [&](int kt) {
        const int b = kt & 3;
        bf16x8 af[8], bv[4];
#pragma unroll
        for (int i = 0; i < 8; ++i)
            af[i] = *reinterpret_cast<const bf16x8*>(
                reinterpret_cast<const char*>(&As[b][0]) + aoff[i]);
#pragma unroll
        for (int n = 0; n < 4; ++n)
            bv[n] = *reinterpret_cast<const bf16x8*>(
                reinterpret_cast<const char*>(&Bs[b][0]) + boff[n]);
        __builtin_amdgcn_s_setprio(1);
#pragma unroll
        for (int i = 0; i < 8; ++i)
#pragma unroll
            for (int n = 0; n < 4; ++n)
                acc[i][n] = __builtin_amdgcn_mfma_f32_16x16x32_bf16(
                    af[i], bv[n], acc[i][n], 0, 0, 0);
        __builtin_amdgcn_s_setprio(0);
    };

    // prologue: stage tiles 0..2, confirm tile 0 (12 issued, wait to 8)
    stage(0); stage(1); stage(2);
    asm volatile("s_waitcnt vmcnt(8)" ::: "memory");
    __builtin_amdgcn_s_barrier();

    // main loop: at end of tile kt, outstanding = {kt+1,kt+2,kt+3} = 12 loads;
    // vmcnt(8) retires the oldest 4 = tile kt+1. Never drains to 0.
#pragma unroll
    for (int kt = 0; kt < 13; ++kt) {
        stage(kt + 3);
        compute(kt);
        asm volatile("s_waitcnt vmcnt(8) lgkmcnt(0)" ::: "memory");
        __builtin_amdgcn_s_barrier();
    }
    // tail: drain 8 -> 4 -> 0
    compute(13);
    asm volatile("s_waitcnt vmcnt(4) lgkmcnt(0)" ::: "memory");
    __builtin_amdgcn_s_barrier();
    compute(14);
    asm volatile("s_waitcnt vmcnt(0) lgkmcnt(0)" ::: "memory");
    __builtin_amdgcn_s_barrier();
    compute(15);

    // epilogue: D layout col=lane&15, row=(lane>>4)*4+j
    const int ldo = NT * 256;
#pragma unroll
    for (int n = 0; n < 4; ++n) {
        int col = n0 + wc * 64 + n * 16 + r16;
        float b = bias[col];
#pragma unroll
        for (int i = 0; i < 8; ++i)
#pragma unroll
            for (int j = 0; j < 4; ++j) {
                int row = m0 + wr * 128 + i * 16 + g * 4 + j;
                if (F32OUT)
                    reinterpret_cast<float*>(outp)[(size_t)row * ldo + col] =
                        acc[i][n][j] + b;
                else
                    reinterpret_cast<bf16*>(outp)[(size_t)row * ldo + col] =
                        cvt(acc[i][n][j] + b);
            }
    }
}

// ---------------------------------------------------------------------------
// Attention: one block per (window, head). 4 waves, each owns 32 query rows.
// Output rows are SCATTERED to attn_g[order[w*128+tok]] so that k_proj's A
// operand is sequential (order[inverse[n]] == n).
// ---------------------------------------------------------------------------
__global__ __launch_bounds__(256) void k_attn(
    const bf16* __restrict__ qkv_s, const int* __restrict__ order,
    bf16* __restrict__ attn_g)
{
    __shared__ __align__(16) char smem[36864 + 64 * 136 * 2];
    __shared__ int ord_s[KWIN];
    bf16 (*Q)[72]   = reinterpret_cast<bf16 (*)[72]>(smem);
    bf16 (*Kt)[72]  = reinterpret_cast<bf16 (*)[72]>(smem + 128 * 72 * 2);
    bf16 (*P)[136]  = reinterpret_cast<bf16 (*)[136]>(smem);          // overlaps Q,K
    bf16 (*Vt)[136] = reinterpret_cast<bf16 (*)[136]>(smem + 36864);  // V transposed

    const int t    = threadIdx.x;
    const int lane = t & 63;
    const int wv   = t >> 6;
    const int g    = lane >> 4, r16 = lane & 15;
    const int h    = blockIdx.x;
    const int w    = blockIdx.y;

    const bf16* base = qkv_s + (size_t)w * KWIN * C3 + h * HD;

    if (t < KWIN) ord_s[t] = order[w * KWIN + t];

    // stage Q, K (row-major [tok][d]) and V transposed [d][tok]
#pragma unroll
    for (int it = 0; it < 4; ++it) {
        int s   = it * 256 + t;      // 0..1023
        int tok = s >> 3;
        int c8  = (s & 7) << 3;
        size_t roff = (size_t)tok * C3 + c8;
        *reinterpret_cast<uint4*>(&Q[tok][c8])  =
            *reinterpret_cast<const uint4*>(base + roff);
        *reinterpret_cast<uint4*>(&Kt[tok][c8]) =
            *reinterpret_cast<const uint4*>(base + roff + CDIM);
        uint4 vvec = *reinterpret_cast<const uint4*>(base + roff + 2 * CDIM);
        const bf16* ve = reinterpret_cast<const bf16*>(&vvec);
#pragma unroll
        for (int i = 0; i < 8; ++i) Vt[c8 + i][tok] = ve[i];
    }
    __syncthreads();

    // S = Q K^T for rows [wv*32, wv*32+32)
    f32x4 sc[2][8];
    const f32x4 z = {0.f, 0.f, 0.f, 0.f};
#pragma unroll
    for (int m = 0; m < 2; ++m)
#pragma unroll
        for (int n = 0; n < 8; ++n) sc[m][n] = z;

#pragma unroll
    for (int ks = 0; ks < 2; ++ks) {
        bf16x8 aq[2];
#pragma unroll
        for (int m = 0; m < 2; ++m)
            aq[m] = *reinterpret_cast<const bf16x8*>(
                &Q[wv * 32 + m * 16 + r16][ks * 32 + g * 8]);
#pragma unroll
        for (int n = 0; n < 8; ++n) {
            bf16x8 bk = *reinterpret_cast<const bf16x8*>(
                &Kt[n * 16 + r16][ks * 32 + g * 8]);
#pragma unroll
            for (int m = 0; m < 2; ++m)
                sc[m][n] = __builtin_amdgcn_mfma_f32_16x16x32_bf16(
                    aq[m], bk, sc[m][n], 0, 0, 0);
        }
    }

    // softmax (f32), row-parallel over 16-lane groups
    const float scale = 0.125f;   // hd^-0.5
    float inv_sum[2][4];
#pragma unroll
    for (int m = 0; m < 2; ++m) {
#pragma unroll
        for (int j = 0; j < 4; ++j) {
            float mx = -3.0e38f;
#pragma unroll
            for (int n = 0; n < 8; ++n) mx = fmaxf(mx, sc[m][n][j]);
            mx = fmaxf(mx, __shfl_xor(mx, 1));
            mx = fmaxf(mx, __shfl_xor(mx, 2));
            mx = fmaxf(mx, __shfl_xor(mx, 4));
            mx = fmaxf(mx, __shfl_xor(mx, 8));
            mx *= scale;
            float ssum = 0.f;
#pragma unroll
            for (int n = 0; n < 8; ++n) {
                float p = __expf(sc[m][n][j] * scale - mx);
                sc[m][n][j] = p;
                ssum += p;
            }
            ssum += __shfl_xor(ssum, 1);
            ssum += __shfl_xor(ssum, 2);
            ssum += __shfl_xor(ssum, 4);
            ssum += __shfl_xor(ssum, 8);
            inv_sum[m][j] = 1.f / ssum;
        }
    }

    __syncthreads();   // all waves done reading Q/Kt before P overwrites them

    // write normalized P (bf16)
#pragma unroll
    for (int m = 0; m < 2; ++m)
#pragma unroll
        for (int n = 0; n < 8; ++n)
#pragma unroll
            for (int j = 0; j < 4; ++j)
                P[wv * 32 + m * 16 + g * 4 + j][n * 16 + r16] =
                    cvt(sc[m][n][j] * inv_sum[m][j]);

    // O = P V   (32x64 per wave)
    f32x4 o[2][4];
#pragma unroll
    for (int m = 0; m < 2; ++m)
#pragma unroll
        for (int n = 0; n < 4; ++n) o[m][n] = z;

#pragma unroll
    for (int kt = 0; kt < 4; ++kt) {
        bf16x8 ap[2];
#pragma unroll
        for (int m = 0; m < 2; ++m)
            ap[m] = *reinterpret_cast<const bf16x8*>(
                &P[wv * 32 + m * 16 + r16][kt * 32 + g * 8]);
#pragma unroll
        for (int n = 0; n < 4; ++n) {
            bf16x8 bv = *reinterpret_cast<const bf16x8*>(
                &Vt[n * 16 + r16][kt * 32 + g * 8]);
#pragma unroll
            for (int m = 0; m < 2; ++m)
                o[m][n] = __builtin_amdgcn_mfma_f32_16x16x32_bf16(
                    ap[m], bv, o[m][n], 0, 0, 0);
        }
    }

    // scatter rows to unserialized position: attn_g[order[i]] = ser[i]
#pragma unroll
    for (int m = 0; m < 2; ++m)
#pragma unroll
        for (int n = 0; n < 4; ++n)
#pragma unroll
            for (int j = 0; j < 4; ++j) {
                int tok  = wv * 32 + m * 16 + g * 4 + j;
                int d    = n * 16 + r16;
                int drow = ord_s[tok];
                attn_g[(size_t)drow * CDIM + h * HD + d] = cvt(o[m][n][j]);
            }
}

// ---------------------------------------------------------------------------
extern "C" void kernel_launch(void* const* d_in, const int* in_sizes, int n_in,
                              void* d_out, int out_size, void* d_ws, size_t ws_size,
                              hipStream_t stream)
{
    const float* feat    = (const float*)d_in[0];
    const float* Wqkv    = (const float*)d_in[1];
    const float* bqkv    = (const float*)d_in[2];
    const float* Wproj   = (const float*)d_in[3];
    const float* bproj   = (const float*)d_in[4];
    const int*   order   = (const int*)d_in[5];
    float* out = (float*)d_out;

    const size_t qkv_bytes  = (size_t)N_PTS * C3 * sizeof(bf16);    // 402.7 MB
    const size_t gat_bytes  = (size_t)N_PTS * CDIM * sizeof(bf16);  // 134.2 MB (feat_g / attn_g)
    const size_t wq_bytes   = (size_t)C3 * CDIM * sizeof(bf16);
    const size_t wp_bytes   = (size_t)CDIM * CDIM * sizeof(bf16);
    if (ws_size < qkv_bytes + gat_bytes + wq_bytes + wp_bytes) return;

    bf16* qkv_s     = (bf16*)d_ws;
    bf16* shared134 = (bf16*)((char*)d_ws + qkv_bytes);   // feat_g, later attn_g
    bf16* Wqkv_t    = (bf16*)((char*)d_ws + qkv_bytes + gat_bytes);
    bf16* Wproj_t   = (bf16*)((char*)d_ws + qkv_bytes + gat_bytes + wq_bytes);

    k_prep<<<dim3((CDIM * C3 + CDIM * CDIM + 255) / 256), 256, 0, stream>>>(
        Wqkv, Wproj, Wqkv_t, Wproj_t);
    k_gather<<<dim3(N_PTS / 2), 256, 0, stream>>>(feat, order, shared134);
    // qkv GEMM: [131072 x 1536] = feat_g @ Wqkv_t^T   (3072 blocks, %8==0)
    k_gemm<false, C3 / 256><<<dim3((N_PTS / 256) * (C3 / 256)), 512, 0, stream>>>(
        shared134, Wqkv_t, bqkv, qkv_s);
    // attention (reads qkv_s, scatters into shared134 = attn_g)
    k_attn<<<dim3(NH, N_PTS / KWIN), 256, 0, stream>>>(qkv_s, order, shared134);
    // proj GEMM: [131072 x 512] = attn_g @ Wproj_t^T  (1024 blocks, f32 out)
    k_gemm<true, CDIM / 256><<<dim3((N_PTS / 256) * (CDIM / 256)), 512, 0, stream>>>(
        shared134, Wproj_t, bproj, out);
}

// Round 5
// 640.084 us; speedup vs baseline: 1.2345x; 1.0256x over previous
//
#include <hip/hip_runtime.h>
#include <hip/hip_bf16.h>
#include <cstdint>
#include <cstddef>

typedef __bf16 bf16;
typedef __bf16 bf16x8 __attribute__((ext_vector_type(8)));
typedef float f32x4 __attribute__((ext_vector_type(4)));

#define N_PTS 131072
#define CDIM  512
#define C3    1536
#define HD    64
#define NH    8
#define KWIN  128

static __device__ __forceinline__ bf16 cvt(float x) { return (bf16)x; }

// async global->LDS, 16B per lane. LDS dest = wave-uniform base + lane*16.
static __device__ __forceinline__ void gld16(const bf16* g, bf16* l) {
    __builtin_amdgcn_global_load_lds(
        (const __attribute__((address_space(1))) void*)g,
        (__attribute__((address_space(3))) void*)l, 16, 0, 0);
}

// ---------------------------------------------------------------------------
// Weight prep: transpose + cast f32 -> bf16.  Wt[col][k] = W[k][col].
// ---------------------------------------------------------------------------
__global__ __launch_bounds__(256) void k_prep(
    const float* __restrict__ Wqkv, const float* __restrict__ Wproj,
    bf16* __restrict__ Wqkv_t, bf16* __restrict__ Wproj_t)
{
    int idx = blockIdx.x * 256 + threadIdx.x;
    if (idx < CDIM * C3) {
        int k = idx / C3, c = idx % C3;
        Wqkv_t[(size_t)c * CDIM + k] = cvt(Wqkv[idx]);
    } else {
        int j = idx - CDIM * C3;
        if (j < CDIM * CDIM) {
            int k = j / CDIM, c = j % CDIM;
            Wproj_t[(size_t)c * CDIM + k] = cvt(Wproj[j]);
        }
    }
}

// ---------------------------------------------------------------------------
// Gather + cast: feat_g[i][:] = bf16(feat[order[i]][:])
// ---------------------------------------------------------------------------
__global__ __launch_bounds__(256) void k_gather(
    const float* __restrict__ feat, const int* __restrict__ order,
    bf16* __restrict__ feat_g)
{
    int row = blockIdx.x * 2 + (threadIdx.x >> 7);
    int c   = (threadIdx.x & 127) << 2;
    int src = order[row];
    float4 v = *reinterpret_cast<const float4*>(feat + (size_t)src * CDIM + c);
    union { bf16 e[4]; uint2 u; } pk;
    pk.e[0] = cvt(v.x); pk.e[1] = cvt(v.y); pk.e[2] = cvt(v.z); pk.e[3] = cvt(v.w);
    *reinterpret_cast<uint2*>(feat_g + (size_t)row * CDIM + c) = pk.u;
}

// ---------------------------------------------------------------------------
// Deep-pipelined bf16 GEMM, 2 blocks/CU for inter-block overlap:
//   out[m, n] = A[m, :] @ Bt[n, :]^T + bias[n]
// 128x256 tile, BK=32, 8 waves (2M x 4N), wave owns 64x64 (4x4 frags,
// acc = 64 AGPR -> total regs <= 128 -> 4 waves/SIMD -> 2 blocks/CU).
// 2-deep LDS ring: (A 8KB + B 16KB) x 2 = 48 KB/block.
// Per tile: compute(kt); lgkm(0); barrier; stage(kt+2); vmcnt(3); barrier.
//   outstanding after stage = {kt+1:3, kt+2:3}; vmcnt(3) confirms kt+1;
//   never drains to 0 in the main loop. WAR on buf[kt&1] guarded by barrier 1.
//
// LDS rotate-permute layout (conflict-free, verified R4: SQ_LDS_BANK_CONFLICT=0):
// chunk (row*4+p) holds k-slot (p-(row>>1))&3; reader uses
// byte = row*64 + (((g+(row>>1))&3)<<4); staging inversely permutes the
// per-lane GLOBAL source (both-sides-or-neither), LDS dest stays linear.
// ---------------------------------------------------------------------------
template <bool F32OUT, int NT>
__global__ __launch_bounds__(512, 4) void k_gemm(
    const bf16* __restrict__ Ag, const bf16* __restrict__ Bt,
    const float* __restrict__ bias, void* __restrict__ outp)
{
    __shared__ __align__(16) bf16 As[2][128 * 32];
    __shared__ __align__(16) bf16 Bs[2][256 * 32];

    const int t    = threadIdx.x;
    const int lane = t & 63;
    const int wv   = t >> 6;          // 0..7
    const int wr   = wv >> 2;         // 0..1  (M half: 64 rows)
    const int wc   = wv & 3;          // 0..3  (N quarter: 64 cols)
    const int g    = lane >> 4, r16 = lane & 15;

    const int nwg = gridDim.x;
    const int bid = blockIdx.x;
    const int swz = (bid & 7) * (nwg >> 3) + (bid >> 3);  // grids are %8==0
    const int m0  = (swz / NT) * 128;
    const int n0  = (swz % NT) * 256;

    // staging: lane owns A chunk L0 (0..511) and B chunks L0, L0+512.
    // chunk L: row=L>>2, phys slot p=L&3, source k-slot=(p-(row>>1))&3.
    const int L0 = wv * 64 + lane;
    const int rA = L0 >> 2,          sA = ((L0 & 3) - (rA >> 1)) & 3;
    const int rB1 = rA + 128,        sB1v = ((L0 & 3) - (rB1 >> 1)) & 3;
    const bf16* srcA  = Ag + (size_t)(m0 + rA) * CDIM + sA * 8;
    const bf16* srcB0 = Bt + (size_t)(n0 + rA) * CDIM + sA * 8;
    const bf16* srcB1 = Bt + (size_t)(n0 + rB1) * CDIM + sB1v * 8;

    // fragment read byte-offsets (rotate-permuted slots)
    int aoff[4], boff[4];
#pragma unroll
    for (int m = 0; m < 4; ++m) {
        int row = wr * 64 + m * 16 + r16;
        aoff[m] = row * 64 + (((g + (row >> 1)) & 3) << 4);
    }
#pragma unroll
    for (int n = 0; n < 4; ++n) {
        int row = wc * 64 + n * 16 + r16;
        boff[n] = row * 64 + (((g + (row >> 1)) & 3) << 4);
    }

    f32x4 acc[4][4];
    const f32x4 z = {0.f, 0.f, 0.f, 0.f};
#pragma unroll
    for (int m = 0; m < 4; ++m)
#pragma unroll
        for (int n = 0; n < 4; ++n) acc[m][n] = z;

    auto stage = [&](int kt) {
        const int b  = kt & 1;
        const int ko = kt * 32;
        gld16(srcA  + ko, &As[b][(size_t)wv * 64 * 8]);
        gld16(srcB0 + ko, &Bs[b][(size_t)wv * 64 * 8]);
        gld16(srcB1 + ko, &Bs[b][(size_t)(512 + wv * 64) * 8]);
    };

    auto compute = [&](int kt) {
        const int b = kt & 1;
        bf16x8 af[4], bv[4];
#pragma unroll
        for (int m = 0; m < 4; ++m)
            af[m] = *reinterpret_cast<const bf16x8*>(
                reinterpret_cast<const char*>(&As[b][0]) + aoff[m]);
#pragma unroll
        for (int n = 0; n < 4; ++n)
            bv[n] = *reinterpret_cast<const bf16x8*>(
                reinterpret_cast<const char*>(&Bs[b][0]) + boff[n]);
        __builtin_amdgcn_s_setprio(1);
#pragma unroll
        for (int m = 0; m < 4; ++m)
#pragma unroll
            for (int n = 0; n < 4; ++n)
                acc[m][n] = __builtin_amdgcn_mfma_f32_16x16x32_bf16(
                    af[m], bv[n], acc[m][n], 0, 0, 0);
        __builtin_amdgcn_s_setprio(0);
    };

    const int NKT = CDIM / 32;   // 16

    // prologue: stage tiles 0,1; confirm tile 0 (tile 1's 3 loads outstanding)
    stage(0); stage(1);
    asm volatile("s_waitcnt vmcnt(3)" ::: "memory");
    __builtin_amdgcn_s_barrier();

#pragma unroll
    for (int kt = 0; kt < NKT - 2; ++kt) {
        compute(kt);
        asm volatile("s_waitcnt lgkmcnt(0)" ::: "memory");
        __builtin_amdgcn_s_barrier();           // all waves done reading buf[kt&1]
        stage(kt + 2);                          // refill buf[kt&1]
        asm volatile("s_waitcnt vmcnt(3)" ::: "memory");  // tile kt+1 resident
        __builtin_amdgcn_s_barrier();
    }
    // tail: tiles 14, 15 already staged
    compute(NKT - 2);
    asm volatile("s_waitcnt vmcnt(0) lgkmcnt(0)" ::: "memory");
    __builtin_amdgcn_s_barrier();
    compute(NKT - 1);

    // epilogue: D layout col=lane&15, row=(lane>>4)*4+j
    const int ldo = NT * 256;
#pragma unroll
    for (int n = 0; n < 4; ++n) {
        int col = n0 + wc * 64 + n * 16 + r16;
        float b = bias[col];
#pragma unroll
        for (int m = 0; m < 4; ++m)
#pragma unroll
            for (int j = 0; j < 4; ++j) {
                int row = m0 + wr * 64 + m * 16 + g * 4 + j;
                if (F32OUT)
                    reinterpret_cast<float*>(outp)[(size_t)row * ldo + col] =
                        acc[m][n][j] + b;
                else
                    reinterpret_cast<bf16*>(outp)[(size_t)row * ldo + col] =
                        cvt(acc[m][n][j] + b);
            }
    }
}

// ---------------------------------------------------------------------------
// Attention: one block per (window, head). 4 waves, each owns 32 query rows.
// Output rows are SCATTERED to attn_g[order[w*128+tok]] so that k_proj's A
// operand is sequential (order[inverse[n]] == n).
// ---------------------------------------------------------------------------
__global__ __launch_bounds__(256) void k_attn(
    const bf16* __restrict__ qkv_s, const int* __restrict__ order,
    bf16* __restrict__ attn_g)
{
    __shared__ __align__(16) char smem[36864 + 64 * 136 * 2];
    __shared__ int ord_s[KWIN];
    bf16 (*Q)[72]   = reinterpret_cast<bf16 (*)[72]>(smem);
    bf16 (*Kt)[72]  = reinterpret_cast<bf16 (*)[72]>(smem + 128 * 72 * 2);
    bf16 (*P)[136]  = reinterpret_cast<bf16 (*)[136]>(smem);          // overlaps Q,K
    bf16 (*Vt)[136] = reinterpret_cast<bf16 (*)[136]>(smem + 36864);  // V transposed

    const int t    = threadIdx.x;
    const int lane = t & 63;
    const int wv   = t >> 6;
    const int g    = lane >> 4, r16 = lane & 15;
    const int h    = blockIdx.x;
    const int w    = blockIdx.y;

    const bf16* base = qkv_s + (size_t)w * KWIN * C3 + h * HD;

    if (t < KWIN) ord_s[t] = order[w * KWIN + t];

    // stage Q, K (row-major [tok][d]) and V transposed [d][tok]
#pragma unroll
    for (int it = 0; it < 4; ++it) {
        int s   = it * 256 + t;      // 0..1023
        int tok = s >> 3;
        int c8  = (s & 7) << 3;
        size_t roff = (size_t)tok * C3 + c8;
        *reinterpret_cast<uint4*>(&Q[tok][c8])  =
            *reinterpret_cast<const uint4*>(base + roff);
        *reinterpret_cast<uint4*>(&Kt[tok][c8]) =
            *reinterpret_cast<const uint4*>(base + roff + CDIM);
        uint4 vvec = *reinterpret_cast<const uint4*>(base + roff + 2 * CDIM);
        const bf16* ve = reinterpret_cast<const bf16*>(&vvec);
#pragma unroll
        for (int i = 0; i < 8; ++i) Vt[c8 + i][tok] = ve[i];
    }
    __syncthreads();

    // S = Q K^T for rows [wv*32, wv*32+32)
    f32x4 sc[2][8];
    const f32x4 z = {0.f, 0.f, 0.f, 0.f};
#pragma unroll
    for (int m = 0; m < 2; ++m)
#pragma unroll
        for (int n = 0; n < 8; ++n) sc[m][n] = z;

#pragma unroll
    for (int ks = 0; ks < 2; ++ks) {
        bf16x8 aq[2];
#pragma unroll
        for (int m = 0; m < 2; ++m)
            aq[m] = *reinterpret_cast<const bf16x8*>(
                &Q[wv * 32 + m * 16 + r16][ks * 32 + g * 8]);
#pragma unroll
        for (int n = 0; n < 8; ++n) {
            bf16x8 bk = *reinterpret_cast<const bf16x8*>(
                &Kt[n * 16 + r16][ks * 32 + g * 8]);
#pragma unroll
            for (int m = 0; m < 2; ++m)
                sc[m][n] = __builtin_amdgcn_mfma_f32_16x16x32_bf16(
                    aq[m], bk, sc[m][n], 0, 0, 0);
        }
    }

    // softmax (f32), row-parallel over 16-lane groups
    const float scale = 0.125f;   // hd^-0.5
    float inv_sum[2][4];
#pragma unroll
    for (int m = 0; m < 2; ++m) {
#pragma unroll
        for (int j = 0; j < 4; ++j) {
            float mx = -3.0e38f;
#pragma unroll
            for (int n = 0; n < 8; ++n) mx = fmaxf(mx, sc[m][n][j]);
            mx = fmaxf(mx, __shfl_xor(mx, 1));
            mx = fmaxf(mx, __shfl_xor(mx, 2));
            mx = fmaxf(mx, __shfl_xor(mx, 4));
            mx = fmaxf(mx, __shfl_xor(mx, 8));
            mx *= scale;
            float ssum = 0.f;
#pragma unroll
            for (int n = 0; n < 8; ++n) {
                float p = __expf(sc[m][n][j] * scale - mx);
                sc[m][n][j] = p;
                ssum += p;
            }
            ssum += __shfl_xor(ssum, 1);
            ssum += __shfl_xor(ssum, 2);
            ssum += __shfl_xor(ssum, 4);
            ssum += __shfl_xor(ssum, 8);
            inv_sum[m][j] = 1.f / ssum;
        }
    }

    __syncthreads();   // all waves done reading Q/Kt before P overwrites them

    // write normalized P (bf16)
#pragma unroll
    for (int m = 0; m < 2; ++m)
#pragma unroll
        for (int n = 0; n < 8; ++n)
#pragma unroll
            for (int j = 0; j < 4; ++j)
                P[wv * 32 + m * 16 + g * 4 + j][n * 16 + r16] =
                    cvt(sc[m][n][j] * inv_sum[m][j]);

    // O = P V   (32x64 per wave)
    f32x4 o[2][4];
#pragma unroll
    for (int m = 0; m < 2; ++m)
#pragma unroll
        for (int n = 0; n < 4; ++n) o[m][n] = z;

#pragma unroll
    for (int kt = 0; kt < 4; ++kt) {
        bf16x8 ap[2];
#pragma unroll
        for (int m = 0; m < 2; ++m)
            ap[m] = *reinterpret_cast<const bf16x8*>(
                &P[wv * 32 + m * 16 + r16][kt * 32 + g * 8]);
#pragma unroll
        for (int n = 0; n < 4; ++n) {
            bf16x8 bv = *reinterpret_cast<const bf16x8*>(
                &Vt[n * 16 + r16][kt * 32 + g * 8]);
#pragma unroll
            for (int m = 0; m < 2; ++m)
                o[m][n] = __builtin_amdgcn_mfma_f32_16x16x32_bf16(
                    ap[m], bv, o[m][n], 0, 0, 0);
        }
    }

    // scatter rows to unserialized position: attn_g[order[i]] = ser[i]
#pragma unroll
    for (int m = 0; m < 2; ++m)
#pragma unroll
        for (int n = 0; n < 4; ++n)
#pragma unroll
            for (int j = 0; j < 4; ++j) {
                int tok  = wv * 32 + m * 16 + g * 4 + j;
                int d    = n * 16 + r16;
                int drow = ord_s[tok];
                attn_g[(size_t)drow * CDIM + h * HD + d] = cvt(o[m][n][j]);
            }
}

// ---------------------------------------------------------------------------
extern "C" void kernel_launch(void* const* d_in, const int* in_sizes, int n_in,
                              void* d_out, int out_size, void* d_ws, size_t ws_size,
                              hipStream_t stream)
{
    const float* feat    = (const float*)d_in[0];
    const float* Wqkv    = (const float*)d_in[1];
    const float* bqkv    = (const float*)d_in[2];
    const float* Wproj   = (const float*)d_in[3];
    const float* bproj   = (const float*)d_in[4];
    const int*   order   = (const int*)d_in[5];
    float* out = (float*)d_out;

    const size_t qkv_bytes  = (size_t)N_PTS * C3 * sizeof(bf16);    // 402.7 MB
    const size_t gat_bytes  = (size_t)N_PTS * CDIM * sizeof(bf16);  // 134.2 MB (feat_g / attn_g)
    const size_t wq_bytes   = (size_t)C3 * CDIM * sizeof(bf16);
    const size_t wp_bytes   = (size_t)CDIM * CDIM * sizeof(bf16);
    if (ws_size < qkv_bytes + gat_bytes + wq_bytes + wp_bytes) return;

    bf16* qkv_s     = (bf16*)d_ws;
    bf16* shared134 = (bf16*)((char*)d_ws + qkv_bytes);   // feat_g, later attn_g
    bf16* Wqkv_t    = (bf16*)((char*)d_ws + qkv_bytes + gat_bytes);
    bf16* Wproj_t   = (bf16*)((char*)d_ws + qkv_bytes + gat_bytes + wq_bytes);

    k_prep<<<dim3((CDIM * C3 + CDIM * CDIM + 255) / 256), 256, 0, stream>>>(
        Wqkv, Wproj, Wqkv_t, Wproj_t);
    k_gather<<<dim3(N_PTS / 2), 256, 0, stream>>>(feat, order, shared134);
    // qkv GEMM: [131072 x 1536] = feat_g @ Wqkv_t^T  (1024 x 6 = 6144 blocks)
    k_gemm<false, C3 / 256><<<dim3((N_PTS / 128) * (C3 / 256)), 512, 0, stream>>>(
        shared134, Wqkv_t, bqkv, qkv_s);
    // attention (reads qkv_s, scatters into shared134 = attn_g)
    k_attn<<<dim3(NH, N_PTS / KWIN), 256, 0, stream>>>(qkv_s, order, shared134);
    // proj GEMM: [131072 x 512] = attn_g @ Wproj_t^T  (1024 x 2 = 2048 blocks)
    k_gemm<true, CDIM / 256><<<dim3((N_PTS / 128) * (CDIM / 256)), 512, 0, stream>>>(
        shared134, Wproj_t, bproj, out);
}